// Round 12
// baseline (906.378 us; speedup 1.0000x reference)
//
#include <hip/hip_runtime.h>

// Problem constants (from reference)
#define N_NODES 12288
#define BATCH   8
#define CH      64
#define NE      245760              // N*KNN
#define ROWS    (N_NODES * BATCH)   // 98304
#define TOT     (ROWS * CH)         // 6291456 floats per activation buffer
#define BN_M    ((float)ROWS)
#define EPS     1e-5f
#define NREP    16                  // stats atomic replicas (1536 blocks -> 96 per addr)

// ---------------- transposes ----------------
__global__ void k_transpose_in(const float* __restrict__ x, float* __restrict__ X) {
    int idx = blockIdx.x * 256 + threadIdx.x;          // index into X [n][b][c]
    int c = idx & 63;
    int b = (idx >> 6) & 7;
    int n = idx >> 9;
    X[idx] = x[(((size_t)b * N_NODES + n) << 6) | c];  // x [b][n][c]
}

__global__ void k_transpose_out(const float* __restrict__ X, float* __restrict__ out) {
    int idx = blockIdx.x * 256 + threadIdx.x;          // index into out [b][n][c]
    int c = idx & 63;
    int bn = idx >> 6;
    int n = bn % N_NODES;
    int b = bn / N_NODES;
    out[idx] = X[(((size_t)n * BATCH + b) << 6) | c];
}

// ---------------- CSR build (once per call, reused by all 8 spmm phases) ------
// zero stats (nf floats) and counts (nc ints) in one dispatch
__global__ void k_zero(float* __restrict__ fp, int nf, int* __restrict__ ip, int nc) {
    int i = blockIdx.x * 256 + threadIdx.x;
    if (i < nf) fp[i] = 0.f;
    else if (i < nf + nc) ip[i - nf] = 0;
}
__global__ void k_hist(const int* __restrict__ rows, int* __restrict__ counts) {
    int e = blockIdx.x * 256 + threadIdx.x;
    if (e < NE) atomicAdd(&counts[rows[e]], 1);
}
__global__ void k_scan(const int* __restrict__ counts, int* __restrict__ offs,
                       int* __restrict__ cursor) {
    __shared__ int sh[1024];
    int t = threadIdx.x;
    int base = t * 12;
    int loc[12];
    int s = 0;
#pragma unroll
    for (int i = 0; i < 12; i++) { loc[i] = s; s += counts[base + i]; }
    sh[t] = s;
    __syncthreads();
    for (int off = 1; off < 1024; off <<= 1) {
        int v = 0;
        if (t >= off) v = sh[t - off];
        __syncthreads();
        if (t >= off) sh[t] += v;
        __syncthreads();
    }
    int pre = t ? sh[t - 1] : 0;
#pragma unroll
    for (int i = 0; i < 12; i++) {
        int o = pre + loc[i];
        offs[base + i] = o;
        cursor[base + i] = o;
    }
    if (t == 1023) offs[N_NODES] = sh[1023];
}
__global__ void k_scatter(const int* __restrict__ rows, const int* __restrict__ cols,
                          const float* __restrict__ vals, int* __restrict__ cursor,
                          int* __restrict__ ccols, float* __restrict__ cvals) {
    int e = blockIdx.x * 256 + threadIdx.x;
    if (e >= NE) return;
    int r = rows[e];
    int pos = atomicAdd(&cursor[r], 1);
    ccols[pos] = cols[e];
    cvals[pos] = vals[e];
}

// ---------------- SpMM: out[n] = alpha * sum_e val*f(Y[col]) + beta*g(z[n]) --
// One node per 128-thread block, no LDS, tiny VGPR -> max occupancy so the
// L2/L3 gather latency (~200-900cy) is hidden by TLP. f/g = bn+relu if set.
template <bool BN_G, bool BN_Z, bool HAS_Z>
__global__ void k_spmm(const int* __restrict__ offs, const int* __restrict__ ccols,
                       const float* __restrict__ cvals, const float* __restrict__ Y,
                       const float* __restrict__ z, const float* __restrict__ ss,
                       float* __restrict__ out, float alpha, float beta) {
    int n = blockIdx.x;
    int t = threadIdx.x;  // 0..127, covers B*C=512 floats as float4
    float sc[4], sh[4];
    if (BN_G || BN_Z) {
        int c0 = (t & 15) * 4;  // channel of component j is c0+j (fixed per thread)
#pragma unroll
        for (int j = 0; j < 4; j++) { sc[j] = ss[c0 + j]; sh[j] = ss[64 + c0 + j]; }
    }
    int s = offs[n], e = offs[n + 1];
    const float4* yb = (const float4*)Y;
    float4 acc = make_float4(0.f, 0.f, 0.f, 0.f);
    for (int i = s; i < e; i++) {
        int col = ccols[i];
        float v = cvals[i];
        float4 yv = yb[((size_t)col << 7) + t];
        if (BN_G) {
            yv.x = fmaxf(yv.x * sc[0] + sh[0], 0.f);
            yv.y = fmaxf(yv.y * sc[1] + sh[1], 0.f);
            yv.z = fmaxf(yv.z * sc[2] + sh[2], 0.f);
            yv.w = fmaxf(yv.w * sc[3] + sh[3], 0.f);
        }
        acc.x += v * yv.x; acc.y += v * yv.y;
        acc.z += v * yv.z; acc.w += v * yv.w;
    }
    size_t o = ((size_t)n << 7) + t;
    float4 r;
    if (HAS_Z) {
        float4 zv = ((const float4*)z)[o];
        if (BN_Z) {
            zv.x = fmaxf(zv.x * sc[0] + sh[0], 0.f);
            zv.y = fmaxf(zv.y * sc[1] + sh[1], 0.f);
            zv.z = fmaxf(zv.z * sc[2] + sh[2], 0.f);
            zv.w = fmaxf(zv.w * sc[3] + sh[3], 0.f);
        }
        r.x = alpha * acc.x + beta * zv.x;
        r.y = alpha * acc.y + beta * zv.y;
        r.z = alpha * acc.z + beta * zv.z;
        r.w = alpha * acc.w + beta * zv.w;
    } else {
        r.x = alpha * acc.x; r.y = alpha * acc.y;
        r.z = alpha * acc.z; r.w = alpha * acc.w;
    }
    ((float4*)out)[o] = r;
}

// ---------------- chebG: acc = f(Y)@W0 + T1@W1 + T2@W2, 64 rows/block --------
// A staged TRANSPOSED in LDS (At[k][row], pad 68 keeps 16B align) so both gemm
// operands are ds_read_b128 (a-read: 4 bcast slots; b-read: 2-way, free).
// 2 tiles = 34.8KB -> 4 blocks/CU. Transposed scalar stores are ~8-way but the
// 1KB/instr LDS-write floor makes that inherent (~5% of the 3072-FMA phase).
// Epilogue: RESID -> X += (acc+bias)*rz ; else write H + BN stats atomics.
template <bool BN, bool RESID>
__global__ void __launch_bounds__(256, 4)
k_chebG(const float* __restrict__ Y, const float* __restrict__ T1,
        const float* __restrict__ T2, const float* __restrict__ W,
        const float* __restrict__ ss, float* __restrict__ stats,
        const float* __restrict__ bias, const float* __restrict__ rz,
        float* __restrict__ X, float* __restrict__ Hout) {
    __shared__ float At[64][68];
    __shared__ float Ws[64][68];
    int t = threadIdx.x;  // 256
    int tx = t & 15, ty = t >> 4;
    size_t rbase = (size_t)blockIdx.x * 64;
    int c0 = (t & 15) * 4;  // column base of this thread's staged float4
    float sc[4], shf[4];
    if (BN) {
#pragma unroll
        for (int j = 0; j < 4; j++) { sc[j] = ss[c0 + j]; shf[j] = ss[64 + c0 + j]; }
    }
    const float* srcs[3] = {Y, T1, T2};
    float acc[4][4] = {};
#pragma unroll
    for (int w = 0; w < 3; w++) {
        if (w) __syncthreads();  // previous gemm done reading LDS
        const float* S = srcs[w];
#pragma unroll
        for (int i = 0; i < 4; i++) {
            int slot = i * 256 + t;  // 0..1023 float4 slots of 64x64 tile
            int r = slot >> 4;
            float4 v = ((const float4*)S)[(rbase << 4) + slot];
            if (BN && w == 0) {
                v.x = fmaxf(v.x * sc[0] + shf[0], 0.f);
                v.y = fmaxf(v.y * sc[1] + shf[1], 0.f);
                v.z = fmaxf(v.z * sc[2] + shf[2], 0.f);
                v.w = fmaxf(v.w * sc[3] + shf[3], 0.f);
            }
            At[c0 + 0][r] = v.x; At[c0 + 1][r] = v.y;
            At[c0 + 2][r] = v.z; At[c0 + 3][r] = v.w;
            float4 wv = ((const float4*)(W + w * 4096))[slot];
            *(float4*)&Ws[r][c0] = wv;
        }
        __syncthreads();
#pragma unroll
        for (int k = 0; k < 64; k++) {
            float4 a = *(const float4*)&At[k][ty * 4];
            float4 b = *(const float4*)&Ws[k][tx * 4];
            acc[0][0] += a.x * b.x; acc[0][1] += a.x * b.y;
            acc[0][2] += a.x * b.z; acc[0][3] += a.x * b.w;
            acc[1][0] += a.y * b.x; acc[1][1] += a.y * b.y;
            acc[1][2] += a.y * b.z; acc[1][3] += a.y * b.w;
            acc[2][0] += a.z * b.x; acc[2][1] += a.z * b.y;
            acc[2][2] += a.z * b.z; acc[2][3] += a.z * b.w;
            acc[3][0] += a.w * b.x; acc[3][1] += a.w * b.y;
            acc[3][2] += a.w * b.z; acc[3][3] += a.w * b.w;
        }
    }

    if (RESID) {
        float bj[4];
#pragma unroll
        for (int j = 0; j < 4; j++) bj[j] = bias[tx * 4 + j];
        float rzv = rz[0];
#pragma unroll
        for (int i = 0; i < 4; i++) {
            size_t f4 = ((rbase + ty * 4 + i) << 4) + tx;
            float4 xv = ((float4*)X)[f4];
            xv.x += (acc[i][0] + bj[0]) * rzv;
            xv.y += (acc[i][1] + bj[1]) * rzv;
            xv.z += (acc[i][2] + bj[2]) * rzv;
            xv.w += (acc[i][3] + bj[3]) * rzv;
            ((float4*)X)[f4] = xv;
        }
    } else {
#pragma unroll
        for (int i = 0; i < 4; i++) {
            size_t f4 = ((rbase + ty * 4 + i) << 4) + tx;
            ((float4*)Hout)[f4] =
                make_float4(acc[i][0], acc[i][1], acc[i][2], acc[i][3]);
        }
        // BN stats: per-thread col partials -> LDS reduce (reuse At) -> atomics
        float s[4] = {}, q[4] = {};
#pragma unroll
        for (int i = 0; i < 4; i++)
#pragma unroll
            for (int j = 0; j < 4; j++) { s[j] += acc[i][j]; q[j] += acc[i][j] * acc[i][j]; }
        __syncthreads();  // gemm reads of At done
        float* redS = &At[0][0];
        float* redQ = redS + 1024;
#pragma unroll
        for (int j = 0; j < 4; j++) {
            redS[ty * 64 + tx * 4 + j] = s[j];
            redQ[ty * 64 + tx * 4 + j] = q[j];
        }
        __syncthreads();
        if (t < 64) {
            float S = 0.f, Q = 0.f;
#pragma unroll
            for (int y = 0; y < 16; y++) { S += redS[y * 64 + t]; Q += redQ[y * 64 + t]; }
            float* st = stats + (blockIdx.x & (NREP - 1)) * 128;
            atomicAdd(&st[t], S);
            atomicAdd(&st[64 + t], Q);
        }
    }
}

// ---------------- BN finalize: stats replicas -> scale/shift -----------------
__global__ void k_bn_finalize(const float* __restrict__ stats, const float* __restrict__ g,
                              const float* __restrict__ b, float* __restrict__ ss) {
    int c = threadIdx.x;  // 64
    float S = 0.f, Q = 0.f;
    for (int r = 0; r < NREP; r++) { S += stats[r * 128 + c]; Q += stats[r * 128 + 64 + c]; }
    float mean = S / BN_M;
    float var = Q / BN_M - mean * mean;
    float sc = g[c] * rsqrtf(var + EPS);
    ss[c] = sc;
    ss[64 + c] = b[c] - mean * sc;
}

extern "C" void kernel_launch(void* const* d_in, const int* in_sizes, int n_in,
                              void* d_out, int out_size, void* d_ws, size_t ws_size,
                              hipStream_t stream) {
    const float* x        = (const float*)d_in[0];
    const int*   lap_rows = (const int*)d_in[1];
    const int*   lap_cols = (const int*)d_in[2];
    const float* lap_vals = (const float*)d_in[3];
    const float* w1_1     = (const float*)d_in[4];
    const float* g1_1     = (const float*)d_in[5];
    const float* b1_1     = (const float*)d_in[6];
    const float* w1_2     = (const float*)d_in[7];
    const float* bias1_2  = (const float*)d_in[8];
    const float* rz1      = (const float*)d_in[9];
    const float* w2_1     = (const float*)d_in[10];
    const float* g2_1     = (const float*)d_in[11];
    const float* b2_1     = (const float*)d_in[12];
    const float* w2_2     = (const float*)d_in[13];
    const float* bias2_2  = (const float*)d_in[14];
    const float* rz2      = (const float*)d_in[15];
    float* out = (float*)d_out;

    // workspace carve-up (~104 MB)
    float* X     = (float*)d_ws;            // TOT
    float* H     = X + TOT;                 // TOT
    float* T1    = H + TOT;                 // TOT
    float* T2    = T1 + TOT;                // TOT
    float* stats = T2 + TOT;                // 2 * NREP * 128 = 4096
    float* ssbuf = stats + 2 * NREP * 128;  // 128
    float* cvals = ssbuf + 128;             // NE
    int* counts  = (int*)(cvals + NE);      // N
    int* offs    = counts + N_NODES;        // N+1
    int* cursor  = offs + N_NODES + 1;      // N
    int* ccols   = cursor + N_NODES;        // NE

    const int EW_BLOCKS = TOT / 256;        // 24576
    const int CB_BLOCKS = ROWS / 64;        // 1536
    const int N_ZERO_ELEMS = 2 * NREP * 128 + N_NODES;  // 4096 floats + 12288 ints

    k_transpose_in<<<EW_BLOCKS, 256, 0, stream>>>(x, X);
    k_zero<<<(N_ZERO_ELEMS + 255) / 256, 256, 0, stream>>>(stats, 2 * NREP * 128, counts, N_NODES);
    k_hist<<<NE / 256, 256, 0, stream>>>(lap_rows, counts);
    k_scan<<<1, 1024, 0, stream>>>(counts, offs, cursor);
    k_scatter<<<NE / 256, 256, 0, stream>>>(lap_rows, lap_cols, lap_vals, cursor, ccols, cvals);

    const float* WA[2] = {w1_1, w2_1};
    const float* Gm[2] = {g1_1, g2_1};
    const float* Bt[2] = {b1_1, b2_1};
    const float* WB[2] = {w1_2, w2_2};
    const float* BI[2] = {bias1_2, bias2_2};
    const float* RZ[2] = {rz1, rz2};

    for (int blk = 0; blk < 2; blk++) {
        float* statsB = stats + blk * NREP * 128;
        // ---- cheb1: H = cheb(X, wA); BN stats folded into gemm epilogue ----
        // T1 = L@X ; T2 = 2*L@T1 - X
        k_spmm<false, false, false><<<N_NODES, 128, 0, stream>>>(
            offs, ccols, cvals, X, nullptr, nullptr, T1, 1.f, 0.f);
        k_spmm<false, false, true><<<N_NODES, 128, 0, stream>>>(
            offs, ccols, cvals, T1, X, nullptr, T2, 2.f, -1.f);
        k_chebG<false, false><<<CB_BLOCKS, 256, 0, stream>>>(
            X, T1, T2, WA[blk], nullptr, statsB, nullptr, nullptr, nullptr, H);
        k_bn_finalize<<<1, 64, 0, stream>>>(statsB, Gm[blk], Bt[blk], ssbuf);
        // ---- cheb2 on f(H)=relu(bn(H)) applied on loads; rezero resid ----
        // T1 = L@f(H) ; T2 = 2*L@T1 - f(H)
        k_spmm<true, false, false><<<N_NODES, 128, 0, stream>>>(
            offs, ccols, cvals, H, nullptr, ssbuf, T1, 1.f, 0.f);
        k_spmm<false, true, true><<<N_NODES, 128, 0, stream>>>(
            offs, ccols, cvals, T1, H, ssbuf, T2, 2.f, -1.f);
        k_chebG<true, true><<<CB_BLOCKS, 256, 0, stream>>>(
            H, T1, T2, WB[blk], ssbuf, nullptr, BI[blk], RZ[blk], X, nullptr);
    }

    k_transpose_out<<<EW_BLOCKS, 256, 0, stream>>>(X, out);
}